// Round 2
// baseline (815.419 us; speedup 1.0000x reference)
//
#include <hip/hip_runtime.h>
#include <hip/hip_bf16.h>

typedef __bf16 bf16x8 __attribute__((ext_vector_type(8)));
typedef float f32x4 __attribute__((ext_vector_type(4)));

__device__ __forceinline__ unsigned short f2bf(float f) {
    unsigned int u = __float_as_uint(f);
    u = (u + 0x7fffu + ((u >> 16) & 1u)) >> 16;
    return (unsigned short)u;
}

__device__ __forceinline__ f32x4 mfma16(bf16x8 a, bf16x8 b, f32x4 c) {
    return __builtin_amdgcn_mfma_f32_16x16x32_bf16(a, b, c, 0, 0, 0);
}

__device__ __forceinline__ void store_c(unsigned short* p, float v) { *p = f2bf(v); }
__device__ __forceinline__ void store_c(float* p, float v) { *p = v; }

// ---------------- cast f32 -> bf16 (vectorized) ----------------
__global__ __launch_bounds__(256) void cast_f32_bf16(const float* __restrict__ in,
                                                     unsigned short* __restrict__ out,
                                                     int n4) {
    int i = blockIdx.x * blockDim.x + threadIdx.x;
    if (i < n4) {
        float4 f = ((const float4*)in)[i];
        ushort4 u;
        u.x = f2bf(f.x); u.y = f2bf(f.y); u.z = f2bf(f.z); u.w = f2bf(f.w);
        ((ushort4*)out)[i] = u;
    }
}

// ---------------- GEMM: C = A (MxK, row-major) * B^T (B is NxK row-major) ----------------
// bf16 inputs, f32 accum. 128x128 tile, BK=64, 4 waves each computing 64x64.
template <typename OUT_T>
__global__ __launch_bounds__(256) void gemm_bt(const unsigned short* __restrict__ A,
                                               const unsigned short* __restrict__ B,
                                               OUT_T* __restrict__ C,
                                               int M, int N, int K) {
    __shared__ __align__(16) unsigned short lA[128 * 64];
    __shared__ __align__(16) unsigned short lB[128 * 64];

    const int tid = threadIdx.x;
    const int w = tid >> 6, lane = tid & 63;
    const int wm = w >> 1, wn = w & 1;
    const int lane16 = lane & 15, g = lane >> 4;
    const int row0 = blockIdx.y * 128, col0 = blockIdx.x * 128;

    f32x4 acc[4][4] = {};

    for (int kt = 0; kt < K; kt += 64) {
#pragma unroll
        for (int i = 0; i < 4; ++i) {
            int ci = (w * 4 + i) * 64 + lane;      // 16B chunk index within 16KB tile
            int grow = ci >> 3;                    // 128B (one row) = 8 chunks
            int gcolb = (ci & 7) * 16;
            size_t aoff = ((size_t)(row0 + grow) * K + kt) * 2 + gcolb;
            size_t boff = ((size_t)(col0 + grow) * K + kt) * 2 + gcolb;
            __builtin_amdgcn_global_load_lds(
                (__attribute__((address_space(1))) void*)(void*)((const char*)A + aoff),
                (__attribute__((address_space(3))) void*)((char*)lA + (w * 4 + i) * 1024),
                16, 0, 0);
            __builtin_amdgcn_global_load_lds(
                (__attribute__((address_space(1))) void*)(void*)((const char*)B + boff),
                (__attribute__((address_space(3))) void*)((char*)lB + (w * 4 + i) * 1024),
                16, 0, 0);
        }
        __syncthreads();
#pragma unroll
        for (int kk = 0; kk < 2; ++kk) {
            bf16x8 aF[4], bF[4];
#pragma unroll
            for (int f = 0; f < 4; ++f) {
                aF[f] = *(const bf16x8*)&lA[(wm * 64 + f * 16 + lane16) * 64 + kk * 32 + g * 8];
                bF[f] = *(const bf16x8*)&lB[(wn * 64 + f * 16 + lane16) * 64 + kk * 32 + g * 8];
            }
#pragma unroll
            for (int fm = 0; fm < 4; ++fm)
#pragma unroll
                for (int fn = 0; fn < 4; ++fn)
                    acc[fm][fn] = mfma16(aF[fm], bF[fn], acc[fm][fn]);
        }
        __syncthreads();
    }

#pragma unroll
    for (int fm = 0; fm < 4; ++fm) {
        int r0 = row0 + wm * 64 + fm * 16 + g * 4;
#pragma unroll
        for (int fn = 0; fn < 4; ++fn) {
            int c = col0 + wn * 64 + fn * 16 + lane16;
#pragma unroll
            for (int r = 0; r < 4; ++r)
                store_c(&C[(size_t)(r0 + r) * N + c], acc[fm][fn][r]);
        }
    }
}

// ---------------- causal flash attention ----------------
// Q,K,V,O: (B*S, 2048) bf16, head h occupies cols [h*128, h*128+128)
// block: 4 waves, each owns 16 q-rows; KV tiles of 64.
__global__ __launch_bounds__(256) void attn_causal(const unsigned short* __restrict__ Q,
                                                   const unsigned short* __restrict__ K,
                                                   const unsigned short* __restrict__ V,
                                                   unsigned short* __restrict__ O) {
    __shared__ __align__(16) unsigned short lK[64 * 128];    // linear (global_load_lds)
    __shared__ __align__(16) unsigned short lVt[128 * 72];   // transposed, padded
    __shared__ __align__(16) unsigned short lP[4][16 * 72];  // per-wave P tile

    const int tid = threadIdx.x, w = tid >> 6, lane = tid & 63;
    const int lane16 = lane & 15, g = lane >> 4;
    const int qt0 = blockIdx.x * 64;
    const int bh = blockIdx.y;
    const int b = bh >> 4, h = bh & 15;
    const size_t rowBase = (size_t)b * 2048;  // b*S
    const int hoff = h * 128;
    const int qr0 = qt0 + w * 16;

    // Q fragments in registers (16 rows x 128 cols)
    bf16x8 qa[4];
    {
        const unsigned short* qp = Q + (rowBase + qr0 + lane16) * 2048 + hoff;
#pragma unroll
        for (int kk = 0; kk < 4; ++kk)
            qa[kk] = *(const bf16x8*)(qp + kk * 32 + g * 8);
    }

    float m_r[4], l_r[4];
    f32x4 accO[8];
#pragma unroll
    for (int r = 0; r < 4; ++r) { m_r[r] = -1e30f; l_r[r] = 0.f; }
#pragma unroll
    for (int f = 0; f < 8; ++f) accO[f] = f32x4{0.f, 0.f, 0.f, 0.f};

    const float scale = 0.08838834764831845f;  // 1/sqrt(128)
    const int nt = qt0 / 64 + 1;

    for (int t = 0; t < nt; ++t) {
        const int kv0 = t * 64;
        __syncthreads();
        // stage K tile (64 x 128) linear
#pragma unroll
        for (int i = 0; i < 4; ++i) {
            int ci = (w * 4 + i) * 64 + lane;   // 16B chunks, 16 per 256B row
            int krow = ci >> 4;
            int kcolb = (ci & 15) * 16;
            size_t goff = ((rowBase + kv0 + krow) * 2048 + hoff) * 2 + kcolb;
            __builtin_amdgcn_global_load_lds(
                (__attribute__((address_space(1))) void*)(void*)((const char*)K + goff),
                (__attribute__((address_space(3))) void*)((char*)lK + (w * 4 + i) * 1024),
                16, 0, 0);
        }
        // stage V transposed: lVt[d][kv]
#pragma unroll
        for (int i = 0; i < 8; ++i) {
            int c4 = i * 256 + tid;            // 2048 chunks of 4 ushorts
            int vrow = c4 >> 5;                // 32 chunks per 128-col row
            int vcol = (c4 & 31) * 4;
            ushort4 d = *(const ushort4*)(V + (rowBase + kv0 + vrow) * 2048 + hoff + vcol);
            lVt[(vcol + 0) * 72 + vrow] = d.x;
            lVt[(vcol + 1) * 72 + vrow] = d.y;
            lVt[(vcol + 2) * 72 + vrow] = d.z;
            lVt[(vcol + 3) * 72 + vrow] = d.w;
        }
        __syncthreads();

        // scores S = Q*K^T (16 x 64), in f32 regs p[n16][r]
        float p[4][4];
#pragma unroll
        for (int n = 0; n < 4; ++n) {
            f32x4 sc = {0.f, 0.f, 0.f, 0.f};
#pragma unroll
            for (int kk = 0; kk < 4; ++kk) {
                bf16x8 kb = *(const bf16x8*)&lK[(n * 16 + lane16) * 128 + kk * 32 + g * 8];
                sc = mfma16(qa[kk], kb, sc);
            }
#pragma unroll
            for (int r = 0; r < 4; ++r) p[n][r] = sc[r] * scale;
        }
        if (t == nt - 1) {  // only the diagonal tile needs masking
#pragma unroll
            for (int n = 0; n < 4; ++n)
#pragma unroll
                for (int r = 0; r < 4; ++r) {
                    int qi = qr0 + g * 4 + r, ki = kv0 + n * 16 + lane16;
                    if (ki > qi) p[n][r] = -1e30f;
                }
        }
        // online softmax; row (g*4+r) lives across the 16 lanes of group g
#pragma unroll
        for (int r = 0; r < 4; ++r) {
            float rm = fmaxf(fmaxf(p[0][r], p[1][r]), fmaxf(p[2][r], p[3][r]));
#pragma unroll
            for (int off = 1; off < 16; off <<= 1)
                rm = fmaxf(rm, __shfl_xor(rm, off, 64));
            float mn = fmaxf(m_r[r], rm);
            float fac = __expf(m_r[r] - mn);
            float rs = 0.f;
#pragma unroll
            for (int n = 0; n < 4; ++n) { p[n][r] = __expf(p[n][r] - mn); rs += p[n][r]; }
#pragma unroll
            for (int off = 1; off < 16; off <<= 1)
                rs += __shfl_xor(rs, off, 64);
            l_r[r] = l_r[r] * fac + rs;
            m_r[r] = mn;
#pragma unroll
            for (int f = 0; f < 8; ++f) accO[f][r] *= fac;
        }
        // P -> LDS (bf16), then read back as A-fragments
#pragma unroll
        for (int n = 0; n < 4; ++n)
#pragma unroll
            for (int r = 0; r < 4; ++r)
                lP[w][(g * 4 + r) * 72 + n * 16 + lane16] = f2bf(p[n][r]);
        asm volatile("s_waitcnt lgkmcnt(0)" ::: "memory");
        // PV: out += P (16x64) * V (64x128)
#pragma unroll
        for (int kk2 = 0; kk2 < 2; ++kk2) {
            bf16x8 pa = *(const bf16x8*)&lP[w][lane16 * 72 + kk2 * 32 + g * 8];
#pragma unroll
            for (int f = 0; f < 8; ++f) {
                bf16x8 vb = *(const bf16x8*)&lVt[(f * 16 + lane16) * 72 + kk2 * 32 + g * 8];
                accO[f] = mfma16(pa, vb, accO[f]);
            }
        }
    }

#pragma unroll
    for (int f = 0; f < 8; ++f)
#pragma unroll
        for (int r = 0; r < 4; ++r) {
            float ov = accO[f][r] / l_r[r];
            O[(rowBase + qr0 + g * 4 + r) * 2048 + hoff + f * 16 + lane16] = f2bf(ov);
        }
}

// ---------------- launch ----------------
extern "C" void kernel_launch(void* const* d_in, const int* in_sizes, int n_in,
                              void* d_out, int out_size, void* d_ws, size_t ws_size,
                              hipStream_t stream) {
    const float* x  = (const float*)d_in[0];
    // d_in[1] = causal mask (static triu(k=1)) — applied analytically
    const float* Wq = (const float*)d_in[2];
    const float* Wk = (const float*)d_in[3];
    const float* Wv = (const float*)d_in[4];
    const float* Wo = (const float*)d_in[5];
    float* out = (float*)d_out;

    char* ws = (char*)d_ws;
    unsigned short* xb = (unsigned short*)(ws);                    // 16MB; reused as attn_out
    unsigned short* q  = (unsigned short*)(ws + (size_t)(16u << 20));
    unsigned short* k  = (unsigned short*)(ws + (size_t)(32u << 20));
    unsigned short* v  = (unsigned short*)(ws + (size_t)(48u << 20));
    unsigned short* wb = (unsigned short*)(ws + (size_t)(64u << 20));

    const int M = 4096, D = 2048;
    dim3 gg(D / 128, M / 128);  // (16, 32)

    cast_f32_bf16<<<(M * D / 4) / 256, 256, 0, stream>>>(x, xb, M * D / 4);

    cast_f32_bf16<<<(D * D / 4) / 256, 256, 0, stream>>>(Wq, wb, D * D / 4);
    gemm_bt<unsigned short><<<gg, 256, 0, stream>>>(xb, wb, q, M, D, D);
    cast_f32_bf16<<<(D * D / 4) / 256, 256, 0, stream>>>(Wk, wb, D * D / 4);
    gemm_bt<unsigned short><<<gg, 256, 0, stream>>>(xb, wb, k, M, D, D);
    cast_f32_bf16<<<(D * D / 4) / 256, 256, 0, stream>>>(Wv, wb, D * D / 4);
    gemm_bt<unsigned short><<<gg, 256, 0, stream>>>(xb, wb, v, M, D, D);

    attn_causal<<<dim3(32, 32), 256, 0, stream>>>(q, k, v, xb);

    cast_f32_bf16<<<(D * D / 4) / 256, 256, 0, stream>>>(Wo, wb, D * D / 4);
    gemm_bt<float><<<gg, 256, 0, stream>>>(xb, wb, out, M, D, D);
}

// Round 5
// 561.688 us; speedup vs baseline: 1.4517x; 1.4517x over previous
//
#include <hip/hip_runtime.h>
#include <hip/hip_bf16.h>

typedef __bf16 bf16x8 __attribute__((ext_vector_type(8)));
typedef float f32x4 __attribute__((ext_vector_type(4)));

__device__ __forceinline__ unsigned short f2bf(float f) {
    unsigned int u = __float_as_uint(f);
    u = (u + 0x7fffu + ((u >> 16) & 1u)) >> 16;
    return (unsigned short)u;
}

__device__ __forceinline__ f32x4 mfma16(bf16x8 a, bf16x8 b, f32x4 c) {
    return __builtin_amdgcn_mfma_f32_16x16x32_bf16(a, b, c, 0, 0, 0);
}

__device__ __forceinline__ void store_c(unsigned short* p, float v) { *p = f2bf(v); }
__device__ __forceinline__ void store_c(float* p, float v) { *p = v; }

// ---------------- cast f32 -> bf16 (vectorized) ----------------
__global__ __launch_bounds__(256) void cast_f32_bf16(const float* __restrict__ in,
                                                     unsigned short* __restrict__ out,
                                                     int n4) {
    int i = blockIdx.x * blockDim.x + threadIdx.x;
    if (i < n4) {
        float4 f = ((const float4*)in)[i];
        ushort4 u;
        u.x = f2bf(f.x); u.y = f2bf(f.y); u.z = f2bf(f.z); u.w = f2bf(f.w);
        ((ushort4*)out)[i] = u;
    }
}

// ---------------- GEMM: C = A (MxK, row-major) * B^T (B is NxK row-major) ----------------
// bf16 inputs, f32 accum. 128x128 tile, BK=64, 4 waves each computing 64x64.
template <typename OUT_T>
__global__ __launch_bounds__(256) void gemm_bt(const unsigned short* __restrict__ A,
                                               const unsigned short* __restrict__ B,
                                               OUT_T* __restrict__ C,
                                               int M, int N, int K) {
    __shared__ __align__(16) unsigned short lA[128 * 64];
    __shared__ __align__(16) unsigned short lB[128 * 64];

    const int tid = threadIdx.x;
    const int w = tid >> 6, lane = tid & 63;
    const int wm = w >> 1, wn = w & 1;
    const int lane16 = lane & 15, g = lane >> 4;
    const int row0 = blockIdx.y * 128, col0 = blockIdx.x * 128;

    f32x4 acc[4][4] = {};

    for (int kt = 0; kt < K; kt += 64) {
#pragma unroll
        for (int i = 0; i < 4; ++i) {
            int ci = (w * 4 + i) * 64 + lane;      // 16B chunk index within 16KB tile
            int grow = ci >> 3;                    // 128B (one row) = 8 chunks
            int gcolb = (ci & 7) * 16;
            size_t aoff = ((size_t)(row0 + grow) * K + kt) * 2 + gcolb;
            size_t boff = ((size_t)(col0 + grow) * K + kt) * 2 + gcolb;
            __builtin_amdgcn_global_load_lds(
                (__attribute__((address_space(1))) void*)(void*)((const char*)A + aoff),
                (__attribute__((address_space(3))) void*)((char*)lA + (w * 4 + i) * 1024),
                16, 0, 0);
            __builtin_amdgcn_global_load_lds(
                (__attribute__((address_space(1))) void*)(void*)((const char*)B + boff),
                (__attribute__((address_space(3))) void*)((char*)lB + (w * 4 + i) * 1024),
                16, 0, 0);
        }
        __syncthreads();
#pragma unroll
        for (int kk = 0; kk < 2; ++kk) {
            bf16x8 aF[4], bF[4];
#pragma unroll
            for (int f = 0; f < 4; ++f) {
                aF[f] = *(const bf16x8*)&lA[(wm * 64 + f * 16 + lane16) * 64 + kk * 32 + g * 8];
                bF[f] = *(const bf16x8*)&lB[(wn * 64 + f * 16 + lane16) * 64 + kk * 32 + g * 8];
            }
#pragma unroll
            for (int fm = 0; fm < 4; ++fm)
#pragma unroll
                for (int fn = 0; fn < 4; ++fn)
                    acc[fm][fn] = mfma16(aF[fm], bF[fn], acc[fm][fn]);
        }
        __syncthreads();
    }

#pragma unroll
    for (int fm = 0; fm < 4; ++fm) {
        int r0 = row0 + wm * 64 + fm * 16 + g * 4;
#pragma unroll
        for (int fn = 0; fn < 4; ++fn) {
            int c = col0 + wn * 64 + fn * 16 + lane16;
#pragma unroll
            for (int r = 0; r < 4; ++r)
                store_c(&C[(size_t)(r0 + r) * N + c], acc[fm][fn][r]);
        }
    }
}

// ---------------- causal flash attention ----------------
// Q,K,V,O: (B*S, 2048) bf16, head h occupies cols [h*128, h*128+128)
// block: 4 waves, each owns 16 q-rows; KV tiles of 64.
// Work-balanced: block bx handles q-tile bx, then q-tile 31-bx (33 KV tiles total).
// lK is XOR-swizzled (chunk ^= row&7) via pre-swizzled global_load_lds source.
__global__ __launch_bounds__(256) void attn_causal(const unsigned short* __restrict__ Q,
                                                   const unsigned short* __restrict__ K,
                                                   const unsigned short* __restrict__ V,
                                                   unsigned short* __restrict__ O) {
    __shared__ __align__(16) unsigned short lK[64 * 128];    // swizzled content
    __shared__ __align__(16) unsigned short lVt[128 * 72];   // transposed, padded
    __shared__ __align__(16) unsigned short lP[4][16 * 72];  // per-wave P tile

    const int tid = threadIdx.x, w = tid >> 6, lane = tid & 63;
    const int lane16 = lane & 15, g = lane >> 4;
    const int bh = blockIdx.y;
    const int b = bh >> 4, h = bh & 15;
    const size_t rowBase = (size_t)b * 2048;  // b*S
    const int hoff = h * 128;
    const float scale = 0.08838834764831845f;  // 1/sqrt(128)

    for (int pass = 0; pass < 2; ++pass) {
        const int qt = pass ? (31 - (int)blockIdx.x) : (int)blockIdx.x;
        const int qt0 = qt * 64;
        const int qr0 = qt0 + w * 16;

        // Q fragments in registers (16 rows x 128 cols)
        bf16x8 qa[4];
        {
            const unsigned short* qp = Q + (rowBase + qr0 + lane16) * 2048 + hoff;
#pragma unroll
            for (int kk = 0; kk < 4; ++kk)
                qa[kk] = *(const bf16x8*)(qp + kk * 32 + g * 8);
        }

        float m_r[4], l_r[4];
        f32x4 accO[8];
#pragma unroll
        for (int r = 0; r < 4; ++r) { m_r[r] = -1e30f; l_r[r] = 0.f; }
#pragma unroll
        for (int f = 0; f < 8; ++f) accO[f] = f32x4{0.f, 0.f, 0.f, 0.f};

        const int nt = qt + 1;

        for (int t = 0; t < nt; ++t) {
            const int kv0 = t * 64;
            __syncthreads();
            // stage K tile (64 x 128) with XOR-swizzled content:
            // LDS chunk p holds global chunk p ^ ((p>>4)&7)  (involution, row bits untouched)
#pragma unroll
            for (int i = 0; i < 4; ++i) {
                int ci = (w * 4 + i) * 64 + lane;   // LDS 16B chunk position
                int krow = ci >> 4;                 // 16 chunks per 256B row
                int kcolb = ((ci & 15) ^ (krow & 7)) * 16;
                size_t goff = ((rowBase + kv0 + krow) * 2048 + hoff) * 2 + kcolb;
                __builtin_amdgcn_global_load_lds(
                    (__attribute__((address_space(1))) void*)(void*)((const char*)K + goff),
                    (__attribute__((address_space(3))) void*)((char*)lK + (w * 4 + i) * 1024),
                    16, 0, 0);
            }
            // stage V transposed: lVt[d][kv]
#pragma unroll
            for (int i = 0; i < 8; ++i) {
                int c4 = i * 256 + tid;            // 2048 chunks of 4 ushorts
                int vrow = c4 >> 5;                // 32 chunks per 128-col row
                int vcol = (c4 & 31) * 4;
                ushort4 d = *(const ushort4*)(V + (rowBase + kv0 + vrow) * 2048 + hoff + vcol);
                lVt[(vcol + 0) * 72 + vrow] = d.x;
                lVt[(vcol + 1) * 72 + vrow] = d.y;
                lVt[(vcol + 2) * 72 + vrow] = d.z;
                lVt[(vcol + 3) * 72 + vrow] = d.w;
            }
            __syncthreads();

            // scores S = Q*K^T (16 x 64), in f32 regs p[n16][r]
            float p[4][4];
#pragma unroll
            for (int n = 0; n < 4; ++n) {
                f32x4 sc = {0.f, 0.f, 0.f, 0.f};
                int row = n * 16 + lane16;
#pragma unroll
                for (int kk = 0; kk < 4; ++kk) {
                    int sw = (kk * 4 + g) ^ (row & 7);   // read-side swizzle
                    bf16x8 kb = *(const bf16x8*)&lK[row * 128 + sw * 8];
                    sc = mfma16(qa[kk], kb, sc);
                }
#pragma unroll
                for (int r = 0; r < 4; ++r) p[n][r] = sc[r] * scale;
            }
            if (t == nt - 1) {  // only the diagonal tile needs masking
#pragma unroll
                for (int n = 0; n < 4; ++n)
#pragma unroll
                    for (int r = 0; r < 4; ++r) {
                        int qi = qr0 + g * 4 + r, ki = kv0 + n * 16 + lane16;
                        if (ki > qi) p[n][r] = -1e30f;
                    }
            }
            // online softmax; row (g*4+r) lives across the 16 lanes of group g
#pragma unroll
            for (int r = 0; r < 4; ++r) {
                float rm = fmaxf(fmaxf(p[0][r], p[1][r]), fmaxf(p[2][r], p[3][r]));
#pragma unroll
                for (int off = 1; off < 16; off <<= 1)
                    rm = fmaxf(rm, __shfl_xor(rm, off, 64));
                float mn = fmaxf(m_r[r], rm);
                float fac = __expf(m_r[r] - mn);
                float rs = 0.f;
#pragma unroll
                for (int n = 0; n < 4; ++n) { p[n][r] = __expf(p[n][r] - mn); rs += p[n][r]; }
#pragma unroll
                for (int off = 1; off < 16; off <<= 1)
                    rs += __shfl_xor(rs, off, 64);
                l_r[r] = l_r[r] * fac + rs;
                m_r[r] = mn;
#pragma unroll
                for (int f = 0; f < 8; ++f) accO[f][r] *= fac;
            }
            // P -> LDS (bf16), then read back as A-fragments
#pragma unroll
            for (int n = 0; n < 4; ++n)
#pragma unroll
                for (int r = 0; r < 4; ++r)
                    lP[w][(g * 4 + r) * 72 + n * 16 + lane16] = f2bf(p[n][r]);
            asm volatile("s_waitcnt lgkmcnt(0)" ::: "memory");
            // PV: out += P (16x64) * V (64x128)
#pragma unroll
            for (int kk2 = 0; kk2 < 2; ++kk2) {
                bf16x8 pa = *(const bf16x8*)&lP[w][lane16 * 72 + kk2 * 32 + g * 8];
#pragma unroll
                for (int f = 0; f < 8; ++f) {
                    bf16x8 vb = *(const bf16x8*)&lVt[(f * 16 + lane16) * 72 + kk2 * 32 + g * 8];
                    accO[f] = mfma16(pa, vb, accO[f]);
                }
            }
        }

#pragma unroll
        for (int f = 0; f < 8; ++f)
#pragma unroll
            for (int r = 0; r < 4; ++r) {
                float ov = accO[f][r] / l_r[r];
                O[(rowBase + qr0 + g * 4 + r) * 2048 + hoff + f * 16 + lane16] = f2bf(ov);
            }
    }
}

// ---------------- launch ----------------
extern "C" void kernel_launch(void* const* d_in, const int* in_sizes, int n_in,
                              void* d_out, int out_size, void* d_ws, size_t ws_size,
                              hipStream_t stream) {
    const float* x  = (const float*)d_in[0];
    // d_in[1] = causal mask (static triu(k=1)) — applied analytically
    const float* Wq = (const float*)d_in[2];
    const float* Wk = (const float*)d_in[3];
    const float* Wv = (const float*)d_in[4];
    const float* Wo = (const float*)d_in[5];
    float* out = (float*)d_out;

    char* ws = (char*)d_ws;
    unsigned short* xb = (unsigned short*)(ws);                    // 16MB; reused as attn_out
    unsigned short* q  = (unsigned short*)(ws + (size_t)(16u << 20));
    unsigned short* k  = (unsigned short*)(ws + (size_t)(32u << 20));
    unsigned short* v  = (unsigned short*)(ws + (size_t)(48u << 20));
    unsigned short* wb = (unsigned short*)(ws + (size_t)(64u << 20));

    const int M = 4096, D = 2048;
    dim3 gg(D / 128, M / 128);  // (16, 32)

    cast_f32_bf16<<<(M * D / 4) / 256, 256, 0, stream>>>(x, xb, M * D / 4);

    cast_f32_bf16<<<(D * D / 4) / 256, 256, 0, stream>>>(Wq, wb, D * D / 4);
    gemm_bt<unsigned short><<<gg, 256, 0, stream>>>(xb, wb, q, M, D, D);
    cast_f32_bf16<<<(D * D / 4) / 256, 256, 0, stream>>>(Wk, wb, D * D / 4);
    gemm_bt<unsigned short><<<gg, 256, 0, stream>>>(xb, wb, k, M, D, D);
    cast_f32_bf16<<<(D * D / 4) / 256, 256, 0, stream>>>(Wv, wb, D * D / 4);
    gemm_bt<unsigned short><<<gg, 256, 0, stream>>>(xb, wb, v, M, D, D);

    attn_causal<<<dim3(16, 32), 256, 0, stream>>>(q, k, v, xb);

    cast_f32_bf16<<<(D * D / 4) / 256, 256, 0, stream>>>(Wo, wb, D * D / 4);
    gemm_bt<float><<<gg, 256, 0, stream>>>(xb, wb, out, M, D, D);
}

// Round 6
// 461.169 us; speedup vs baseline: 1.7682x; 1.2180x over previous
//
#include <hip/hip_runtime.h>
#include <hip/hip_bf16.h>

typedef __bf16 bf16x8 __attribute__((ext_vector_type(8)));
typedef float f32x4 __attribute__((ext_vector_type(4)));
typedef unsigned short ushort8v __attribute__((ext_vector_type(8)));

__device__ __forceinline__ unsigned short f2bf(float f) {
    unsigned int u = __float_as_uint(f);
    u = (u + 0x7fffu + ((u >> 16) & 1u)) >> 16;
    return (unsigned short)u;
}

__device__ __forceinline__ f32x4 mfma16(bf16x8 a, bf16x8 b, f32x4 c) {
    return __builtin_amdgcn_mfma_f32_16x16x32_bf16(a, b, c, 0, 0, 0);
}

__device__ __forceinline__ void store_c(unsigned short* p, float v) { *p = f2bf(v); }
__device__ __forceinline__ void store_c(float* p, float v) { *p = v; }

// ---------------- cast f32 -> bf16 (vectorized) ----------------
__global__ __launch_bounds__(256) void cast_f32_bf16(const float* __restrict__ in,
                                                     unsigned short* __restrict__ out,
                                                     int n4) {
    int i = blockIdx.x * blockDim.x + threadIdx.x;
    if (i < n4) {
        float4 f = ((const float4*)in)[i];
        ushort4 u;
        u.x = f2bf(f.x); u.y = f2bf(f.y); u.z = f2bf(f.z); u.w = f2bf(f.w);
        ((ushort4*)out)[i] = u;
    }
}

// ---------------- V transpose: v(token,channel) -> vt(bh*128+d, s) ----------------
// v: (4096 x 2048) bf16, row = b*2048+s, col = h*128+d
// vt: (4096 x 2048) bf16, row = (b*16+h)*128+d, col = s
__global__ __launch_bounds__(256) void transpose_v(const unsigned short* __restrict__ v,
                                                   unsigned short* __restrict__ vt) {
    __shared__ unsigned short t[64][65];
    const int tid = threadIdx.x;
    const int s0 = blockIdx.x * 64;
    const int d0 = blockIdx.y * 64;
    const int bh = blockIdx.z;            // b*16+h
    const int b = bh >> 4, h = bh & 15;

#pragma unroll
    for (int i = 0; i < 2; ++i) {
        int idx = i * 256 + tid;
        int r = idx >> 3, c8 = (idx & 7) * 8;
        ushort8v d = *(const ushort8v*)(v + ((size_t)(b * 2048 + s0 + r)) * 2048 + h * 128 + d0 + c8);
#pragma unroll
        for (int j = 0; j < 8; ++j) t[r][c8 + j] = d[j];
    }
    __syncthreads();
#pragma unroll
    for (int i = 0; i < 2; ++i) {
        int idx = i * 256 + tid;
        int dr = idx >> 3, sc8 = (idx & 7) * 8;
        ushort8v o;
#pragma unroll
        for (int j = 0; j < 8; ++j) o[j] = t[sc8 + j][dr];
        *(ushort8v*)(vt + ((size_t)(bh * 128 + d0 + dr)) * 2048 + s0 + sc8) = o;
    }
}

// ---------------- GEMM: C = A (MxK, row-major) * B^T (B is NxK row-major) ----------------
// bf16 inputs, f32 accum. 128x128 tile, BK=64, 4 waves each computing 64x64.
template <typename OUT_T>
__global__ __launch_bounds__(256) void gemm_bt(const unsigned short* __restrict__ A,
                                               const unsigned short* __restrict__ B,
                                               OUT_T* __restrict__ C,
                                               int M, int N, int K) {
    __shared__ __align__(16) unsigned short lA[128 * 64];
    __shared__ __align__(16) unsigned short lB[128 * 64];

    const int tid = threadIdx.x;
    const int w = tid >> 6, lane = tid & 63;
    const int wm = w >> 1, wn = w & 1;
    const int lane16 = lane & 15, g = lane >> 4;
    const int row0 = blockIdx.y * 128, col0 = blockIdx.x * 128;

    f32x4 acc[4][4] = {};

    for (int kt = 0; kt < K; kt += 64) {
#pragma unroll
        for (int i = 0; i < 4; ++i) {
            int ci = (w * 4 + i) * 64 + lane;      // 16B chunk index within 16KB tile
            int grow = ci >> 3;                    // 128B (one row) = 8 chunks
            int gcolb = (ci & 7) * 16;
            size_t aoff = ((size_t)(row0 + grow) * K + kt) * 2 + gcolb;
            size_t boff = ((size_t)(col0 + grow) * K + kt) * 2 + gcolb;
            __builtin_amdgcn_global_load_lds(
                (__attribute__((address_space(1))) void*)(void*)((const char*)A + aoff),
                (__attribute__((address_space(3))) void*)((char*)lA + (w * 4 + i) * 1024),
                16, 0, 0);
            __builtin_amdgcn_global_load_lds(
                (__attribute__((address_space(1))) void*)(void*)((const char*)B + boff),
                (__attribute__((address_space(3))) void*)((char*)lB + (w * 4 + i) * 1024),
                16, 0, 0);
        }
        __syncthreads();
#pragma unroll
        for (int kk = 0; kk < 2; ++kk) {
            bf16x8 aF[4], bF[4];
#pragma unroll
            for (int f = 0; f < 4; ++f) {
                aF[f] = *(const bf16x8*)&lA[(wm * 64 + f * 16 + lane16) * 64 + kk * 32 + g * 8];
                bF[f] = *(const bf16x8*)&lB[(wn * 64 + f * 16 + lane16) * 64 + kk * 32 + g * 8];
            }
#pragma unroll
            for (int fm = 0; fm < 4; ++fm)
#pragma unroll
                for (int fn = 0; fn < 4; ++fn)
                    acc[fm][fn] = mfma16(aF[fm], bF[fn], acc[fm][fn]);
        }
        __syncthreads();
    }

#pragma unroll
    for (int fm = 0; fm < 4; ++fm) {
        int r0 = row0 + wm * 64 + fm * 16 + g * 4;
#pragma unroll
        for (int fn = 0; fn < 4; ++fn) {
            int c = col0 + wn * 64 + fn * 16 + lane16;
#pragma unroll
            for (int r = 0; r < 4; ++r)
                store_c(&C[(size_t)(r0 + r) * N + c], acc[fm][fn][r]);
        }
    }
}

// ---------------- causal flash attention ----------------
// Q,K: (B*S, 2048) bf16 (head h at cols h*128..); VT: (bh*128+d, s); O: (B*S, 2048)
// block: 4 waves, each owns 16 q-rows; KV tiles of 64.
// Work-balanced: block bx handles q-tile bx, then q-tile 31-bx (33 KV tiles total).
// lK and lVt are chunk-XOR-swizzled via pre-swizzled global_load_lds source.
__global__ __launch_bounds__(256) void attn_causal(const unsigned short* __restrict__ Q,
                                                   const unsigned short* __restrict__ K,
                                                   const unsigned short* __restrict__ VT,
                                                   unsigned short* __restrict__ O) {
    __shared__ __align__(16) unsigned short lK[64 * 128];    // swizzled content
    __shared__ __align__(16) unsigned short lVt[128 * 64];   // swizzled content (d-major)
    __shared__ __align__(16) unsigned short lP[4][16 * 80];  // per-wave P tile

    const int tid = threadIdx.x, w = tid >> 6, lane = tid & 63;
    const int lane16 = lane & 15, g = lane >> 4;
    const int bh = blockIdx.y;
    const int b = bh >> 4, h = bh & 15;
    const size_t rowBase = (size_t)b * 2048;  // b*S
    const int hoff = h * 128;
    const float scale = 0.08838834764831845f;  // 1/sqrt(128)

    for (int pass = 0; pass < 2; ++pass) {
        const int qt = pass ? (31 - (int)blockIdx.x) : (int)blockIdx.x;
        const int qt0 = qt * 64;
        const int qr0 = qt0 + w * 16;

        // Q fragments in registers (16 rows x 128 cols)
        bf16x8 qa[4];
        {
            const unsigned short* qp = Q + (rowBase + qr0 + lane16) * 2048 + hoff;
#pragma unroll
            for (int kk = 0; kk < 4; ++kk)
                qa[kk] = *(const bf16x8*)(qp + kk * 32 + g * 8);
        }

        float m_r[4], l_r[4];
        f32x4 accO[8];
#pragma unroll
        for (int r = 0; r < 4; ++r) { m_r[r] = -1e30f; l_r[r] = 0.f; }
#pragma unroll
        for (int f = 0; f < 8; ++f) accO[f] = f32x4{0.f, 0.f, 0.f, 0.f};

        const int nt = qt + 1;

        for (int t = 0; t < nt; ++t) {
            const int kv0 = t * 64;
            __syncthreads();
            // stage K tile (64 rows x 128 cols): LDS chunk (row, c) holds global chunk c^(row&7)
#pragma unroll
            for (int i = 0; i < 4; ++i) {
                int ci = (w * 4 + i) * 64 + lane;   // LDS 16B chunk position
                int krow = ci >> 4;                 // 16 chunks per 256B row
                int kcolb = ((ci & 15) ^ (krow & 7)) * 16;
                size_t goff = ((rowBase + kv0 + krow) * 2048 + hoff) * 2 + kcolb;
                __builtin_amdgcn_global_load_lds(
                    (__attribute__((address_space(1))) void*)(void*)((const char*)K + goff),
                    (__attribute__((address_space(3))) void*)((char*)lK + (w * 4 + i) * 1024),
                    16, 0, 0);
            }
            // stage Vt tile (128 d-rows x 64 kv cols): 8 chunks/row, chunk c holds c^(d&7)
#pragma unroll
            for (int i = 0; i < 4; ++i) {
                int ci = (w * 4 + i) * 64 + lane;   // LDS 16B chunk position (0..1023)
                int drow = ci >> 3;                 // 8 chunks per 128B row
                int slot = (ci & 7) ^ (drow & 7);
                size_t goff = ((size_t)(bh * 128 + drow) * 2048 + kv0 + slot * 8) * 2;
                __builtin_amdgcn_global_load_lds(
                    (__attribute__((address_space(1))) void*)(void*)((const char*)VT + goff),
                    (__attribute__((address_space(3))) void*)((char*)lVt + (w * 4 + i) * 1024),
                    16, 0, 0);
            }
            __syncthreads();

            // scores S = Q*K^T (16 x 64), in f32 regs p[n16][r]
            float p[4][4];
#pragma unroll
            for (int n = 0; n < 4; ++n) {
                f32x4 sc = {0.f, 0.f, 0.f, 0.f};
                int row = n * 16 + lane16;
#pragma unroll
                for (int kk = 0; kk < 4; ++kk) {
                    int sw = (kk * 4 + g) ^ (row & 7);   // read-side swizzle
                    bf16x8 kb = *(const bf16x8*)&lK[row * 128 + sw * 8];
                    sc = mfma16(qa[kk], kb, sc);
                }
#pragma unroll
                for (int r = 0; r < 4; ++r) p[n][r] = sc[r] * scale;
            }
            if (t == nt - 1) {  // only the diagonal tile needs masking
#pragma unroll
                for (int n = 0; n < 4; ++n)
#pragma unroll
                    for (int r = 0; r < 4; ++r) {
                        int qi = qr0 + g * 4 + r, ki = kv0 + n * 16 + lane16;
                        if (ki > qi) p[n][r] = -1e30f;
                    }
            }
            // online softmax; row (g*4+r) lives across the 16 lanes of group g
#pragma unroll
            for (int r = 0; r < 4; ++r) {
                float rm = fmaxf(fmaxf(p[0][r], p[1][r]), fmaxf(p[2][r], p[3][r]));
#pragma unroll
                for (int off = 1; off < 16; off <<= 1)
                    rm = fmaxf(rm, __shfl_xor(rm, off, 64));
                float mn = fmaxf(m_r[r], rm);
                float fac = __expf(m_r[r] - mn);
                float rs = 0.f;
#pragma unroll
                for (int n = 0; n < 4; ++n) { p[n][r] = __expf(p[n][r] - mn); rs += p[n][r]; }
#pragma unroll
                for (int off = 1; off < 16; off <<= 1)
                    rs += __shfl_xor(rs, off, 64);
                l_r[r] = l_r[r] * fac + rs;
                m_r[r] = mn;
#pragma unroll
                for (int f = 0; f < 8; ++f) accO[f][r] *= fac;
            }
            // P -> LDS (bf16), then read back as A-fragments
#pragma unroll
            for (int n = 0; n < 4; ++n)
#pragma unroll
                for (int r = 0; r < 4; ++r)
                    lP[w][(g * 4 + r) * 80 + n * 16 + lane16] = f2bf(p[n][r]);
            asm volatile("s_waitcnt lgkmcnt(0)" ::: "memory");
            // PV: out += P (16x64) * V (64x128); V^T fragments from swizzled lVt
#pragma unroll
            for (int kk2 = 0; kk2 < 2; ++kk2) {
                bf16x8 pa = *(const bf16x8*)&lP[w][lane16 * 80 + kk2 * 32 + g * 8];
#pragma unroll
                for (int f = 0; f < 8; ++f) {
                    int row = f * 16 + lane16;
                    int slot = (kk2 * 4 + g) ^ (row & 7);
                    bf16x8 vb = *(const bf16x8*)&lVt[row * 64 + slot * 8];
                    accO[f] = mfma16(pa, vb, accO[f]);
                }
            }
        }

#pragma unroll
        for (int f = 0; f < 8; ++f)
#pragma unroll
            for (int r = 0; r < 4; ++r) {
                float ov = accO[f][r] / l_r[r];
                O[(rowBase + qr0 + g * 4 + r) * 2048 + hoff + f * 16 + lane16] = f2bf(ov);
            }
    }
}

// ---------------- launch ----------------
extern "C" void kernel_launch(void* const* d_in, const int* in_sizes, int n_in,
                              void* d_out, int out_size, void* d_ws, size_t ws_size,
                              hipStream_t stream) {
    const float* x  = (const float*)d_in[0];
    // d_in[1] = causal mask (static triu(k=1)) — applied analytically
    const float* Wq = (const float*)d_in[2];
    const float* Wk = (const float*)d_in[3];
    const float* Wv = (const float*)d_in[4];
    const float* Wo = (const float*)d_in[5];
    float* out = (float*)d_out;

    char* ws = (char*)d_ws;
    unsigned short* xb = (unsigned short*)(ws);                    // 16MB; x bf16, later vt
    unsigned short* q  = (unsigned short*)(ws + (size_t)(16u << 20));
    unsigned short* k  = (unsigned short*)(ws + (size_t)(32u << 20));
    unsigned short* v  = (unsigned short*)(ws + (size_t)(48u << 20)); // v bf16, later attn O
    unsigned short* wb = (unsigned short*)(ws + (size_t)(64u << 20)); // 8MB weight buf
    unsigned short* vt = xb;   // vt reuses xb region (x dead after QKV gemms)
    unsigned short* o  = v;    // attn output reuses v region (v dead after transpose)

    const int M = 4096, D = 2048;
    dim3 gg(D / 128, M / 128);  // (16, 32)

    cast_f32_bf16<<<(M * D / 4) / 256, 256, 0, stream>>>(x, xb, M * D / 4);

    cast_f32_bf16<<<(D * D / 4) / 256, 256, 0, stream>>>(Wq, wb, D * D / 4);
    gemm_bt<unsigned short><<<gg, 256, 0, stream>>>(xb, wb, q, M, D, D);
    cast_f32_bf16<<<(D * D / 4) / 256, 256, 0, stream>>>(Wk, wb, D * D / 4);
    gemm_bt<unsigned short><<<gg, 256, 0, stream>>>(xb, wb, k, M, D, D);
    cast_f32_bf16<<<(D * D / 4) / 256, 256, 0, stream>>>(Wv, wb, D * D / 4);
    gemm_bt<unsigned short><<<gg, 256, 0, stream>>>(xb, wb, v, M, D, D);

    transpose_v<<<dim3(32, 2, 32), 256, 0, stream>>>(v, vt);

    attn_causal<<<dim3(16, 32), 256, 0, stream>>>(q, k, vt, o);

    cast_f32_bf16<<<(D * D / 4) / 256, 256, 0, stream>>>(Wo, wb, D * D / 4);
    gemm_bt<float><<<gg, 256, 0, stream>>>(o, wb, out, M, D, D);
}